// Round 3
// baseline (742.518 us; speedup 1.0000x reference)
//
#include <hip/hip_runtime.h>
#include <hip/hip_bf16.h>
#include <hip/hip_fp8.h>

#define T_TOK 4096
#define DIM 1024
#define VOCAB 32000
#define BM 256
#define BN 256
#define KT 128               // fp8 bytes of K per tile = one MFMA K
#define NKT (DIM / KT)       // 8
#define NVT (VOCAB / BN)     // 125 vocab tiles
#define NMT (T_TOK / BM)     // 16 token tiles

typedef __attribute__((ext_vector_type(4))) int i32x4;
typedef __attribute__((ext_vector_type(8))) int i32x8;
typedef __attribute__((ext_vector_type(4))) float f32x4;

typedef __attribute__((address_space(1))) const unsigned int ga_u32;
typedef __attribute__((address_space(3))) unsigned int ls_u32;

__device__ __forceinline__ void gload16(const void* g, void* l) {
  __builtin_amdgcn_global_load_lds((ga_u32*)g, (ls_u32*)l, 16, 0, 0);
}

// fp32 -> fp8 e4m3 (OCP) with global scale, 16 elems/thread
__global__ void quant_kernel(const float* __restrict__ in, unsigned char* __restrict__ out,
                             long long n, float scale) {
  long long i = ((long long)blockIdx.x * blockDim.x + threadIdx.x) * 16;
  if (i + 15 < n) {
    union { unsigned char b[16]; uint4 u; } p;
    const float4* src = (const float4*)(in + i);
#pragma unroll
    for (int q = 0; q < 4; ++q) {
      float4 v = src[q];
      p.b[q * 4 + 0] = __hip_fp8_e4m3(v.x * scale).__x;
      p.b[q * 4 + 1] = __hip_fp8_e4m3(v.y * scale).__x;
      p.b[q * 4 + 2] = __hip_fp8_e4m3(v.z * scale).__x;
      p.b[q * 4 + 3] = __hip_fp8_e4m3(v.w * scale).__x;
    }
    *(uint4*)(out + i) = p.u;
  }
}

// 256x256-tile 8-wave MX-fp8 GEMM (K=128 MFMA), dbuf k-tiles, fused exp-row-sum.
// H stored x2^4 (scale byte 123 = 2^-4), W stored x2^6 (scale byte 121 = 2^-6).
// partial[vtile][token] = sum over tile's 256 vocab cols of exp(logit + bias)
__global__ __launch_bounds__(512, 2) void gemm_ce_kernel(
    const unsigned char* __restrict__ A, const unsigned char* __restrict__ W,
    const float* __restrict__ bias, float* __restrict__ partial) {
  __shared__ unsigned char Als[2][BM * KT];   // 2 x 32 KB
  __shared__ unsigned char Bls[2][BN * KT];   // 2 x 32 KB
  __shared__ float red[BM][4];

  const int t = threadIdx.x;
  const int lane = t & 63;
  const int wid = t >> 6;        // 0..7
  const int wm = wid >> 2;       // 0..1 (M half)
  const int wn = wid & 3;        // 0..3 (N quarter)
  const int lr = lane & 15;
  const int lq = lane >> 4;      // 0..3 (k-quarter: 32 bytes each)

  const int b = blockIdx.x;
  const int w = (b & 7) * 250 + (b >> 3);   // bijective XCD swizzle (2000 % 8 == 0)
  const int vt = w >> 4;                    // vt-major within XCD -> W-panel L2 reuse
  const int mt = w & 15;
  const int m0 = mt * BM;
  const int n0 = vt * BN;

  // staging: thread t -> row sr + i*64, 16B-slot s8; source slot pre-swizzled (rule #21)
  const int s8 = t & 7, sr = t >> 3;
  const int gslot = s8 ^ (sr & 7);          // row&7 == sr&7 since i*64 % 8 == 0
  const unsigned char* agp = A + (size_t)(m0 + sr) * DIM + gslot * 16;
  const unsigned char* bgp = W + (size_t)(n0 + sr) * DIM + gslot * 16;

  // ds_read offsets: lane reads row r, k-bytes lq*32..lq*32+31 (two b128, slots 2lq, 2lq+1)
  // swizzle: slot ^= (r & 7)  -> 8 lanes per 4-bank group, conflict-free
  int aoff[8], boff[4];
#pragma unroll
  for (int mi = 0; mi < 8; ++mi) {
    int r = wm * 128 + mi * 16 + lr;
    aoff[mi] = r * KT + ((2 * lq) ^ (r & 7)) * 16;
  }
#pragma unroll
  for (int ni = 0; ni < 4; ++ni) {
    int r = wn * 64 + ni * 16 + lr;
    boff[ni] = r * KT + ((2 * lq) ^ (r & 7)) * 16;
  }

  f32x4 acc[8][4];
#pragma unroll
  for (int i = 0; i < 8; ++i)
#pragma unroll
    for (int j = 0; j < 4; ++j) acc[i][j] = (f32x4){0.f, 0.f, 0.f, 0.f};

#define STAGE_A(KTI) { \
    unsigned char* d_ = &Als[(KTI) & 1][0] + t * 16; \
    const unsigned char* g_ = agp + (KTI) * KT; \
    gload16(g_, d_); \
    gload16(g_ + 64 * DIM, d_ + 8192); \
    gload16(g_ + 128 * DIM, d_ + 16384); \
    gload16(g_ + 192 * DIM, d_ + 24576); }

#define STAGE_B(KTI) { \
    unsigned char* d_ = &Bls[(KTI) & 1][0] + t * 16; \
    const unsigned char* g_ = bgp + (KTI) * KT; \
    gload16(g_, d_); \
    gload16(g_ + 64 * DIM, d_ + 8192); \
    gload16(g_ + 128 * DIM, d_ + 16384); \
    gload16(g_ + 192 * DIM, d_ + 24576); }

  // assemble 32B fragment from two swizzled b128s (slot XOR 1 <=> byte XOR 16)
#define LDFRAG(base, off, dst) { \
    i32x4 lo_ = *(const i32x4*)((base) + (off)); \
    i32x4 hi_ = *(const i32x4*)((base) + ((off) ^ 16)); \
    dst[0] = lo_[0]; dst[1] = lo_[1]; dst[2] = lo_[2]; dst[3] = lo_[3]; \
    dst[4] = hi_[0]; dst[5] = hi_[1]; dst[6] = hi_[2]; dst[7] = hi_[3]; }

#define MM(mi, ni, av, bv) \
  acc[mi][ni] = __builtin_amdgcn_mfma_scale_f32_16x16x128_f8f6f4( \
      av, bv, acc[mi][ni], 0, 0, 0, 123, 0, 121);

  // prologue: stage k-tile 0, drain once
  STAGE_A(0) STAGE_B(0)
  asm volatile("s_waitcnt vmcnt(0)" ::: "memory");
  __builtin_amdgcn_s_barrier();

#pragma unroll
  for (int kt = 0; kt < NKT; ++kt) {
    const unsigned char* Ab = &Als[kt & 1][0];
    const unsigned char* Bb = &Bls[kt & 1][0];
    if (kt < NKT - 1) STAGE_A(kt + 1)          // into opposite buffer
    i32x8 fb0, fb1, fb2, fb3, fa0, fa1, fa2, fa3;
    LDFRAG(Bb, boff[0], fb0) LDFRAG(Bb, boff[1], fb1)
    LDFRAG(Bb, boff[2], fb2) LDFRAG(Bb, boff[3], fb3)
    LDFRAG(Ab, aoff[0], fa0) LDFRAG(Ab, aoff[1], fa1)
    LDFRAG(Ab, aoff[2], fa2) LDFRAG(Ab, aoff[3], fa3)
    __builtin_amdgcn_s_setprio(1);
    MM(0, 0, fa0, fb0) MM(0, 1, fa0, fb1) MM(0, 2, fa0, fb2) MM(0, 3, fa0, fb3)
    MM(1, 0, fa1, fb0) MM(1, 1, fa1, fb1) MM(1, 2, fa1, fb2) MM(1, 3, fa1, fb3)
    MM(2, 0, fa2, fb0) MM(2, 1, fa2, fb1) MM(2, 2, fa2, fb2) MM(2, 3, fa2, fb3)
    MM(3, 0, fa3, fb0) MM(3, 1, fa3, fb1) MM(3, 2, fa3, fb2) MM(3, 3, fa3, fb3)
    __builtin_amdgcn_s_setprio(0);
    if (kt < NKT - 1) STAGE_B(kt + 1)
    i32x8 fa4, fa5, fa6, fa7;
    LDFRAG(Ab, aoff[4], fa4) LDFRAG(Ab, aoff[5], fa5)
    LDFRAG(Ab, aoff[6], fa6) LDFRAG(Ab, aoff[7], fa7)
    __builtin_amdgcn_s_setprio(1);
    MM(4, 0, fa4, fb0) MM(4, 1, fa4, fb1) MM(4, 2, fa4, fb2) MM(4, 3, fa4, fb3)
    MM(5, 0, fa5, fb0) MM(5, 1, fa5, fb1) MM(5, 2, fa5, fb2) MM(5, 3, fa5, fb3)
    MM(6, 0, fa6, fb0) MM(6, 1, fa6, fb1) MM(6, 2, fa6, fb2) MM(6, 3, fa6, fb3)
    MM(7, 0, fa7, fb0) MM(7, 1, fa7, fb1) MM(7, 2, fa7, fb2) MM(7, 3, fa7, fb3)
    __builtin_amdgcn_s_setprio(0);
    asm volatile("s_waitcnt vmcnt(0)" ::: "memory");   // next tile's 8 stages done
    __builtin_amdgcn_s_barrier();
    __builtin_amdgcn_sched_barrier(0);
  }

  // Epilogue: per token row, sum exp(logit+bias) over tile's 256 vocab cols.
  // C/D layout: vocab col = lane&15 (+ni*16+wn*64), token row = (lane>>4)*4+reg (+mi*16+wm*128)
  __syncthreads();
  float bc[4];
#pragma unroll
  for (int ni = 0; ni < 4; ++ni) bc[ni] = bias[n0 + wn * 64 + ni * 16 + lr];
#pragma unroll
  for (int mi = 0; mi < 8; ++mi) {
    float s0 = 0.f, s1 = 0.f, s2 = 0.f, s3 = 0.f;
#pragma unroll
    for (int ni = 0; ni < 4; ++ni) {
      s0 += __expf(acc[mi][ni][0] + bc[ni]);
      s1 += __expf(acc[mi][ni][1] + bc[ni]);
      s2 += __expf(acc[mi][ni][2] + bc[ni]);
      s3 += __expf(acc[mi][ni][3] + bc[ni]);
    }
#pragma unroll
    for (int off = 1; off < 16; off <<= 1) {
      s0 += __shfl_xor(s0, off);
      s1 += __shfl_xor(s1, off);
      s2 += __shfl_xor(s2, off);
      s3 += __shfl_xor(s3, off);
    }
    if (lr == 0) {
      int rbase = wm * 128 + mi * 16 + lq * 4;
      red[rbase + 0][wn] = s0;
      red[rbase + 1][wn] = s1;
      red[rbase + 2][wn] = s2;
      red[rbase + 3][wn] = s3;
    }
  }
  __syncthreads();
  if (t < BM) {
    partial[(size_t)vt * T_TOK + m0 + t] = red[t][0] + red[t][1] + red[t][2] + red[t][3];
  }
}

// tgt[t] = dot(H[t], W[labels[t]]) + bias[labels[t]] in exact fp32 (one wave per token)
__global__ void tgt_kernel(const float* __restrict__ H, const float* __restrict__ W,
                           const float* __restrict__ bias, const int* __restrict__ labels,
                           float* __restrict__ tgt) {
  int tok = blockIdx.x * 4 + (threadIdx.x >> 6);
  int lane = threadIdx.x & 63;
  int lab = labels[tok];
  const float4* h = (const float4*)(H + (size_t)tok * DIM);
  const float4* w = (const float4*)(W + (size_t)lab * DIM);
  float s = 0.f;
#pragma unroll
  for (int j = 0; j < 4; ++j) {
    float4 a = h[lane + 64 * j];
    float4 bb = w[lane + 64 * j];
    s += a.x * bb.x + a.y * bb.y + a.z * bb.z + a.w * bb.w;
  }
#pragma unroll
  for (int off = 32; off > 0; off >>= 1) s += __shfl_xor(s, off);
  if (lane == 0) tgt[tok] = s + bias[lab];
}

// per-token: logz - tgt, weighted; wave-reduce -> per-block partials (deterministic)
__global__ void loss_a_kernel(const float* __restrict__ partial, const float* __restrict__ tgt,
                              const float* __restrict__ lw, float* __restrict__ npart,
                              float* __restrict__ dpart) {
  int tok = blockIdx.x * 64 + threadIdx.x;
  float s = 0.f;
  for (int v = 0; v < NVT; ++v) s += partial[(size_t)v * T_TOK + tok];
  float w = lw[tok];
  float num = w * (logf(s) - tgt[tok]);
#pragma unroll
  for (int off = 32; off > 0; off >>= 1) {
    num += __shfl_xor(num, off);
    w += __shfl_xor(w, off);
  }
  if (threadIdx.x == 0) {
    npart[blockIdx.x] = num;
    dpart[blockIdx.x] = w;
  }
}

__global__ void loss_b_kernel(const float* __restrict__ npart, const float* __restrict__ dpart,
                              float* __restrict__ out) {
  float num = npart[threadIdx.x];
  float den = dpart[threadIdx.x];
#pragma unroll
  for (int off = 32; off > 0; off >>= 1) {
    num += __shfl_xor(num, off);
    den += __shfl_xor(den, off);
  }
  if (threadIdx.x == 0) out[0] = num / den;
}

extern "C" void kernel_launch(void* const* d_in, const int* in_sizes, int n_in,
                              void* d_out, int out_size, void* d_ws, size_t ws_size,
                              hipStream_t stream) {
  const float* H = (const float*)d_in[0];
  const float* Wt = (const float*)d_in[1];
  const float* bias = (const float*)d_in[2];
  const int* labels = (const int*)d_in[3];
  const float* lw = (const float*)d_in[4];
  float* out = (float*)d_out;

  // ws layout (bytes):
  //   Wq  u8 [VOCAB][DIM]      = 32,768,000
  //   Hq  u8 [T_TOK][DIM]      =  4,194,304
  //   partial f32 [NVT][T_TOK] =  2,048,000
  //   tgt f32 [T_TOK]; npart/dpart f32 [64]x2
  char* ws = (char*)d_ws;
  unsigned char* Wq = (unsigned char*)ws;
  unsigned char* Hq = (unsigned char*)(ws + 32768000);
  float* partial = (float*)(ws + 32768000 + 4194304);
  float* tgt = (float*)(ws + 32768000 + 4194304 + 2048000);
  float* npart = tgt + T_TOK;
  float* dpart = npart + 64;

  hipLaunchKernelGGL(quant_kernel, dim3(((long long)VOCAB * DIM) / 4096), dim3(256), 0, stream,
                     Wt, Wq, (long long)VOCAB * DIM, 64.0f);   // W x 2^6
  hipLaunchKernelGGL(quant_kernel, dim3(((long long)T_TOK * DIM) / 4096), dim3(256), 0, stream,
                     H, Hq, (long long)T_TOK * DIM, 16.0f);    // H x 2^4
  hipLaunchKernelGGL(gemm_ce_kernel, dim3(NVT * NMT), dim3(512), 0, stream,
                     Hq, Wq, bias, partial);
  hipLaunchKernelGGL(tgt_kernel, dim3(T_TOK / 4), dim3(256), 0, stream,
                     H, Wt, bias, labels, tgt);
  hipLaunchKernelGGL(loss_a_kernel, dim3(T_TOK / 64), dim3(64), 0, stream,
                     partial, tgt, lw, npart, dpart);
  hipLaunchKernelGGL(loss_b_kernel, dim3(1), dim3(64), 0, stream,
                     npart, dpart, out);
}

// Round 4
// 638.098 us; speedup vs baseline: 1.1636x; 1.1636x over previous
//
#include <hip/hip_runtime.h>
#include <hip/hip_bf16.h>
#include <hip/hip_fp8.h>

#define T_TOK 4096
#define DIM 1024
#define VOCAB 32000
#define BM 256
#define BN 256
#define KT 128               // fp8 bytes of K per tile = one MFMA K
#define NKT (DIM / KT)       // 8
#define NVT (VOCAB / BN)     // 125 vocab tiles
#define NMT (T_TOK / BM)     // 16 token tiles

typedef __attribute__((ext_vector_type(4))) int i32x4;
typedef __attribute__((ext_vector_type(8))) int i32x8;
typedef __attribute__((ext_vector_type(4))) float f32x4;

typedef __attribute__((address_space(1))) const unsigned int ga_u32;
typedef __attribute__((address_space(3))) unsigned int ls_u32;

__device__ __forceinline__ void gload16(const void* g, void* l) {
  __builtin_amdgcn_global_load_lds((ga_u32*)g, (ls_u32*)l, 16, 0, 0);
}

// fp32 -> fp8 e4m3 (OCP) with global scale, 16 elems/thread
__global__ void quant_kernel(const float* __restrict__ in, unsigned char* __restrict__ out,
                             long long n, float scale) {
  long long i = ((long long)blockIdx.x * blockDim.x + threadIdx.x) * 16;
  if (i + 15 < n) {
    union { unsigned char b[16]; uint4 u; } p;
    const float4* src = (const float4*)(in + i);
#pragma unroll
    for (int q = 0; q < 4; ++q) {
      float4 v = src[q];
      p.b[q * 4 + 0] = __hip_fp8_e4m3(v.x * scale).__x;
      p.b[q * 4 + 1] = __hip_fp8_e4m3(v.y * scale).__x;
      p.b[q * 4 + 2] = __hip_fp8_e4m3(v.z * scale).__x;
      p.b[q * 4 + 3] = __hip_fp8_e4m3(v.w * scale).__x;
    }
    *(uint4*)(out + i) = p.u;
  }
}

// 256x256-tile 8-wave MX-fp8 GEMM (K=128 MFMA), dbuf k-tiles, fused exp-row-sum.
// H stored x2^4 (scale byte 123 = 2^-4), W stored x2^6 (scale byte 121 = 2^-6).
// partial[vtile][token] = sum over tile's 256 vocab cols of exp(logit + bias)
__global__ __launch_bounds__(512, 2) void gemm_ce_kernel(
    const unsigned char* __restrict__ A, const unsigned char* __restrict__ W,
    const float* __restrict__ bias, float* __restrict__ partial) {
  __shared__ unsigned char Als[2][BM * KT];   // 2 x 32 KB
  __shared__ unsigned char Bls[2][BN * KT];   // 2 x 32 KB
  __shared__ float red[BM][4];

  const int t = threadIdx.x;
  const int lane = t & 63;
  const int wid = t >> 6;        // 0..7
  const int wm = wid >> 2;       // 0..1 (M half)
  const int wn = wid & 3;        // 0..3 (N quarter)
  const int lr = lane & 15;
  const int lq = lane >> 4;      // 0..3 (k-quarter: 32 bytes each)

  const int b = blockIdx.x;
  const int w = (b & 7) * 250 + (b >> 3);   // bijective XCD swizzle (2000 % 8 == 0)
  const int vt = w >> 4;                    // vt-major within XCD -> W-panel L2 reuse
  const int mt = w & 15;
  const int m0 = mt * BM;
  const int n0 = vt * BN;

  // staging: thread t -> row sr + i*64, 16B-slot s8; source slot pre-swizzled (rule #21)
  const int s8 = t & 7, sr = t >> 3;
  const int gslot = s8 ^ (sr & 7);          // row&7 == sr&7 since i*64 % 8 == 0
  const unsigned char* agp = A + (size_t)(m0 + sr) * DIM + gslot * 16;
  const unsigned char* bgp = W + (size_t)(n0 + sr) * DIM + gslot * 16;

  // ds_read offsets: lane reads row r, k-bytes lq*32..lq*32+31 (two b128, slots 2lq, 2lq+1)
  // swizzle: slot ^= (r & 7)  -> uniform 8 lanes per 16B slot group = minimal for b128
  int aoff[8], boff[4];
#pragma unroll
  for (int mi = 0; mi < 8; ++mi) {
    int r = wm * 128 + mi * 16 + lr;
    aoff[mi] = r * KT + ((2 * lq) ^ (r & 7)) * 16;
  }
#pragma unroll
  for (int ni = 0; ni < 4; ++ni) {
    int r = wn * 64 + ni * 16 + lr;
    boff[ni] = r * KT + ((2 * lq) ^ (r & 7)) * 16;
  }

  f32x4 acc[8][4];
#pragma unroll
  for (int i = 0; i < 8; ++i)
#pragma unroll
    for (int j = 0; j < 4; ++j) acc[i][j] = (f32x4){0.f, 0.f, 0.f, 0.f};

#define STAGE_A(KTI) { \
    unsigned char* d_ = &Als[(KTI) & 1][0] + t * 16; \
    const unsigned char* g_ = agp + (KTI) * KT; \
    gload16(g_, d_); \
    gload16(g_ + 64 * DIM, d_ + 8192); \
    gload16(g_ + 128 * DIM, d_ + 16384); \
    gload16(g_ + 192 * DIM, d_ + 24576); }

#define STAGE_B(KTI) { \
    unsigned char* d_ = &Bls[(KTI) & 1][0] + t * 16; \
    const unsigned char* g_ = bgp + (KTI) * KT; \
    gload16(g_, d_); \
    gload16(g_ + 64 * DIM, d_ + 8192); \
    gload16(g_ + 128 * DIM, d_ + 16384); \
    gload16(g_ + 192 * DIM, d_ + 24576); }

  // assemble 32B fragment from two swizzled b128s (slot XOR 1 <=> byte XOR 16)
#define LDFRAG(base, off, dst) { \
    i32x4 lo_ = *(const i32x4*)((base) + (off)); \
    i32x4 hi_ = *(const i32x4*)((base) + ((off) ^ 16)); \
    dst[0] = lo_[0]; dst[1] = lo_[1]; dst[2] = lo_[2]; dst[3] = lo_[3]; \
    dst[4] = hi_[0]; dst[5] = hi_[1]; dst[6] = hi_[2]; dst[7] = hi_[3]; }

#define MM(mi, ni, av, bv) \
  acc[mi][ni] = __builtin_amdgcn_mfma_scale_f32_16x16x128_f8f6f4( \
      av, bv, acc[mi][ni], 0, 0, 0, 123, 0, 121);

  // prologue: stage k-tile 0, drain once
  STAGE_A(0) STAGE_B(0)
  asm volatile("s_waitcnt vmcnt(0)" ::: "memory");
  __builtin_amdgcn_s_barrier();

  // NOTE: kt loop deliberately NOT unrolled; fa fragments loaded per-mi.
  // Peak regs ~ acc(128) + fb(32) + fa(~16) + addr(~30) < 256 cap for 8-wave blocks.
  for (int kt = 0; kt < NKT; ++kt) {
    const unsigned char* Ab = &Als[kt & 1][0];
    const unsigned char* Bb = &Bls[kt & 1][0];
    const bool more = (kt < NKT - 1);
    if (more) STAGE_A(kt + 1)          // into opposite buffer
    i32x8 fb0, fb1, fb2, fb3;
    LDFRAG(Bb, boff[0], fb0) LDFRAG(Bb, boff[1], fb1)
    LDFRAG(Bb, boff[2], fb2) LDFRAG(Bb, boff[3], fb3)
#pragma unroll
    for (int mi = 0; mi < 4; ++mi) {
      i32x8 fa;
      LDFRAG(Ab, aoff[mi], fa)
      __builtin_amdgcn_s_setprio(1);
      MM(mi, 0, fa, fb0) MM(mi, 1, fa, fb1) MM(mi, 2, fa, fb2) MM(mi, 3, fa, fb3)
      __builtin_amdgcn_s_setprio(0);
    }
    if (more) STAGE_B(kt + 1)
#pragma unroll
    for (int mi = 4; mi < 8; ++mi) {
      i32x8 fa;
      LDFRAG(Ab, aoff[mi], fa)
      __builtin_amdgcn_s_setprio(1);
      MM(mi, 0, fa, fb0) MM(mi, 1, fa, fb1) MM(mi, 2, fa, fb2) MM(mi, 3, fa, fb3)
      __builtin_amdgcn_s_setprio(0);
    }
    asm volatile("s_waitcnt vmcnt(0)" ::: "memory");   // next tile's 8 stages done
    __builtin_amdgcn_s_barrier();
    __builtin_amdgcn_sched_barrier(0);
  }

  // Epilogue: per token row, sum exp(logit+bias) over tile's 256 vocab cols.
  // C/D layout: vocab col = lane&15 (+ni*16+wn*64), token row = (lane>>4)*4+reg (+mi*16+wm*128)
  __syncthreads();
  float bc[4];
#pragma unroll
  for (int ni = 0; ni < 4; ++ni) bc[ni] = bias[n0 + wn * 64 + ni * 16 + lr];
#pragma unroll
  for (int mi = 0; mi < 8; ++mi) {
    float s0 = 0.f, s1 = 0.f, s2 = 0.f, s3 = 0.f;
#pragma unroll
    for (int ni = 0; ni < 4; ++ni) {
      s0 += __expf(acc[mi][ni][0] + bc[ni]);
      s1 += __expf(acc[mi][ni][1] + bc[ni]);
      s2 += __expf(acc[mi][ni][2] + bc[ni]);
      s3 += __expf(acc[mi][ni][3] + bc[ni]);
    }
#pragma unroll
    for (int off = 1; off < 16; off <<= 1) {
      s0 += __shfl_xor(s0, off);
      s1 += __shfl_xor(s1, off);
      s2 += __shfl_xor(s2, off);
      s3 += __shfl_xor(s3, off);
    }
    if (lr == 0) {
      int rbase = wm * 128 + mi * 16 + lq * 4;
      red[rbase + 0][wn] = s0;
      red[rbase + 1][wn] = s1;
      red[rbase + 2][wn] = s2;
      red[rbase + 3][wn] = s3;
    }
  }
  __syncthreads();
  if (t < BM) {
    partial[(size_t)vt * T_TOK + m0 + t] = red[t][0] + red[t][1] + red[t][2] + red[t][3];
  }
}

// tgt[t] = dot(H[t], W[labels[t]]) + bias[labels[t]] in exact fp32 (one wave per token)
__global__ void tgt_kernel(const float* __restrict__ H, const float* __restrict__ W,
                           const float* __restrict__ bias, const int* __restrict__ labels,
                           float* __restrict__ tgt) {
  int tok = blockIdx.x * 4 + (threadIdx.x >> 6);
  int lane = threadIdx.x & 63;
  int lab = labels[tok];
  const float4* h = (const float4*)(H + (size_t)tok * DIM);
  const float4* w = (const float4*)(W + (size_t)lab * DIM);
  float s = 0.f;
#pragma unroll
  for (int j = 0; j < 4; ++j) {
    float4 a = h[lane + 64 * j];
    float4 bb = w[lane + 64 * j];
    s += a.x * bb.x + a.y * bb.y + a.z * bb.z + a.w * bb.w;
  }
#pragma unroll
  for (int off = 32; off > 0; off >>= 1) s += __shfl_xor(s, off);
  if (lane == 0) tgt[tok] = s + bias[lab];
}

// per-token: logz - tgt, weighted; wave-reduce -> per-block partials (deterministic)
__global__ void loss_a_kernel(const float* __restrict__ partial, const float* __restrict__ tgt,
                              const float* __restrict__ lw, float* __restrict__ npart,
                              float* __restrict__ dpart) {
  int tok = blockIdx.x * 64 + threadIdx.x;
  float s = 0.f;
  for (int v = 0; v < NVT; ++v) s += partial[(size_t)v * T_TOK + tok];
  float w = lw[tok];
  float num = w * (logf(s) - tgt[tok]);
#pragma unroll
  for (int off = 32; off > 0; off >>= 1) {
    num += __shfl_xor(num, off);
    w += __shfl_xor(w, off);
  }
  if (threadIdx.x == 0) {
    npart[blockIdx.x] = num;
    dpart[blockIdx.x] = w;
  }
}

__global__ void loss_b_kernel(const float* __restrict__ npart, const float* __restrict__ dpart,
                              float* __restrict__ out) {
  float num = npart[threadIdx.x];
  float den = dpart[threadIdx.x];
#pragma unroll
  for (int off = 32; off > 0; off >>= 1) {
    num += __shfl_xor(num, off);
    den += __shfl_xor(den, off);
  }
  if (threadIdx.x == 0) out[0] = num / den;
}

extern "C" void kernel_launch(void* const* d_in, const int* in_sizes, int n_in,
                              void* d_out, int out_size, void* d_ws, size_t ws_size,
                              hipStream_t stream) {
  const float* H = (const float*)d_in[0];
  const float* Wt = (const float*)d_in[1];
  const float* bias = (const float*)d_in[2];
  const int* labels = (const int*)d_in[3];
  const float* lw = (const float*)d_in[4];
  float* out = (float*)d_out;

  // ws layout (bytes):
  //   Wq  u8 [VOCAB][DIM]      = 32,768,000
  //   Hq  u8 [T_TOK][DIM]      =  4,194,304
  //   partial f32 [NVT][T_TOK] =  2,048,000
  //   tgt f32 [T_TOK]; npart/dpart f32 [64]x2
  char* ws = (char*)d_ws;
  unsigned char* Wq = (unsigned char*)ws;
  unsigned char* Hq = (unsigned char*)(ws + 32768000);
  float* partial = (float*)(ws + 32768000 + 4194304);
  float* tgt = (float*)(ws + 32768000 + 4194304 + 2048000);
  float* npart = tgt + T_TOK;
  float* dpart = npart + 64;

  hipLaunchKernelGGL(quant_kernel, dim3(((long long)VOCAB * DIM) / 4096), dim3(256), 0, stream,
                     Wt, Wq, (long long)VOCAB * DIM, 64.0f);   // W x 2^6
  hipLaunchKernelGGL(quant_kernel, dim3(((long long)T_TOK * DIM) / 4096), dim3(256), 0, stream,
                     H, Hq, (long long)T_TOK * DIM, 16.0f);    // H x 2^4
  hipLaunchKernelGGL(gemm_ce_kernel, dim3(NVT * NMT), dim3(512), 0, stream,
                     Hq, Wq, bias, partial);
  hipLaunchKernelGGL(tgt_kernel, dim3(T_TOK / 4), dim3(256), 0, stream,
                     H, Wt, bias, labels, tgt);
  hipLaunchKernelGGL(loss_a_kernel, dim3(T_TOK / 64), dim3(64), 0, stream,
                     partial, tgt, lw, npart, dpart);
  hipLaunchKernelGGL(loss_b_kernel, dim3(1), dim3(64), 0, stream,
                     npart, dpart, out);
}

// Round 5
// 215.817 us; speedup vs baseline: 3.4405x; 2.9567x over previous
//
#include <hip/hip_runtime.h>
#include <hip/hip_bf16.h>
#include <hip/hip_fp8.h>

#define T_TOK 4096
#define DIM 1024
#define VOCAB 32000
#define BM 256
#define BN 256
#define KT 128               // fp8 bytes of K per tile = one MFMA K
#define NKT (DIM / KT)       // 8
#define NVT (VOCAB / BN)     // 125 vocab tiles
#define NMT (T_TOK / BM)     // 16 token tiles

typedef __attribute__((ext_vector_type(4))) int i32x4;
typedef __attribute__((ext_vector_type(8))) int i32x8;
typedef __attribute__((ext_vector_type(4))) float f32x4;

typedef __attribute__((address_space(1))) const unsigned int ga_u32;
typedef __attribute__((address_space(3))) unsigned int ls_u32;

__device__ __forceinline__ void gload16(const void* g, void* l) {
  __builtin_amdgcn_global_load_lds((ga_u32*)g, (ls_u32*)l, 16, 0, 0);
}

// fp32 -> fp8 e4m3 (OCP) with global scale, 16 elems/thread
__global__ void quant_kernel(const float* __restrict__ in, unsigned char* __restrict__ out,
                             long long n, float scale) {
  long long i = ((long long)blockIdx.x * blockDim.x + threadIdx.x) * 16;
  if (i + 15 < n) {
    union { unsigned char b[16]; uint4 u; } p;
    const float4* src = (const float4*)(in + i);
#pragma unroll
    for (int q = 0; q < 4; ++q) {
      float4 v = src[q];
      p.b[q * 4 + 0] = __hip_fp8_e4m3(v.x * scale).__x;
      p.b[q * 4 + 1] = __hip_fp8_e4m3(v.y * scale).__x;
      p.b[q * 4 + 2] = __hip_fp8_e4m3(v.z * scale).__x;
      p.b[q * 4 + 3] = __hip_fp8_e4m3(v.w * scale).__x;
    }
    *(uint4*)(out + i) = p.u;
  }
}

// 256x256-tile 8-wave MX-fp8 GEMM (K=128 MFMA), dbuf k-tiles, fused exp-row-sum.
// LDS per k-tile operand = two [256][64] subtiles (64-B rows, R2-verified swizzle).
// H stored x2^4 (scale 123 = 2^-4), W stored x2^6 (scale 121 = 2^-6).
// partial[vtile][token] = sum over tile's 256 vocab cols of exp(logit + bias)
__global__ __launch_bounds__(512, 2) void gemm_ce_kernel(
    const unsigned char* __restrict__ A, const unsigned char* __restrict__ W,
    const float* __restrict__ bias, float* __restrict__ partial) {
  __shared__ unsigned char Als[2][2 * 16384];   // [buf][sub*16384 + row*64 + slot*16]
  __shared__ unsigned char Bls[2][2 * 16384];
  __shared__ float red[BM][4];

  const int t = threadIdx.x;
  const int lane = t & 63;
  const int wid = t >> 6;        // 0..7
  const int wm = wid >> 2;       // 0..1 (M half)
  const int wn = wid & 3;        // 0..3 (N quarter)
  const int lr = lane & 15;
  const int lq = lane >> 4;      // 0..3 (k-quarter: 32 bytes of the 128-B K)

  const int b = blockIdx.x;
  const int w = (b & 7) * 250 + (b >> 3);   // bijective XCD swizzle (2000 % 8 == 0)
  const int vt = w >> 4;                    // vt-major within XCD -> W-panel L2 reuse
  const int mt = w & 15;
  const int m0 = mt * BM;
  const int n0 = vt * BN;

  // staging: thread t -> LDS (row t>>2, slot t&3) of each (sub,rowhalf) 8KB region.
  // LDS[row][s] holds global slot s ^ ((row>>1)&3)  (involution; reader XORs same mask)
  const int gslot = (t & 3) ^ ((t >> 3) & 3);
  const unsigned char* agp = A + (size_t)(m0 + (t >> 2)) * DIM + gslot * 16;
  const unsigned char* bgp = W + (size_t)(n0 + (t >> 2)) * DIM + gslot * 16;

  // reader offsets: fragment k-bytes lq*32..+31 -> subtile lq>>1, slot pair (lq&1)*2.
  // off = sub*16384 + r*64 + ((pair+h) ^ ((r>>1)&3))*16 ; h=1 is off^16.
  int aoff[8], boff[4];
#pragma unroll
  for (int mi = 0; mi < 8; ++mi) {
    int r = wm * 128 + mi * 16 + lr;
    aoff[mi] = (lq >> 1) * 16384 + r * 64 + ((((lq & 1) << 1) ^ ((r >> 1) & 3)) << 4);
  }
#pragma unroll
  for (int ni = 0; ni < 4; ++ni) {
    int r = wn * 64 + ni * 16 + lr;
    boff[ni] = (lq >> 1) * 16384 + r * 64 + ((((lq & 1) << 1) ^ ((r >> 1) & 3)) << 4);
  }

  f32x4 acc[8][4];
#pragma unroll
  for (int i = 0; i < 8; ++i)
#pragma unroll
    for (int j = 0; j < 4; ++j) acc[i][j] = (f32x4){0.f, 0.f, 0.f, 0.f};

#define STAGE_A(KTI) { \
    unsigned char* d_ = &Als[(KTI) & 1][0] + t * 16; \
    const unsigned char* g_ = agp + ((KTI) & 7) * KT; \
    gload16(g_, d_);                                 /* sub0 rows 0-127   */ \
    gload16(g_ + (size_t)128 * DIM, d_ + 8192);      /* sub0 rows 128-255 */ \
    gload16(g_ + 64, d_ + 16384);                    /* sub1 rows 0-127   */ \
    gload16(g_ + 64 + (size_t)128 * DIM, d_ + 24576);/* sub1 rows 128-255 */ }

#define STAGE_B(KTI) { \
    unsigned char* d_ = &Bls[(KTI) & 1][0] + t * 16; \
    const unsigned char* g_ = bgp + ((KTI) & 7) * KT; \
    gload16(g_, d_); \
    gload16(g_ + (size_t)128 * DIM, d_ + 8192); \
    gload16(g_ + 64, d_ + 16384); \
    gload16(g_ + 64 + (size_t)128 * DIM, d_ + 24576); }

  // load fragment halves DIRECTLY into dst's two quads (no temps -> no reg bloat)
#define LDFRAG(base, off, dst) { \
    *(i32x4*)&(dst) = *(const i32x4*)((base) + (off)); \
    *((i32x4*)&(dst) + 1) = *(const i32x4*)((base) + ((off) ^ 16)); }

#define MM(mi, ni, av, bv) \
  acc[mi][ni] = __builtin_amdgcn_mfma_scale_f32_16x16x128_f8f6f4( \
      av, bv, acc[mi][ni], 0, 0, 0, 123, 0, 121);

  // prologue: stage k-tile 0, drain once
  STAGE_A(0) STAGE_B(0)
  asm volatile("s_waitcnt vmcnt(0)" ::: "memory");
  __builtin_amdgcn_s_barrier();

#pragma unroll 1
  for (int kt = 0; kt < NKT; ++kt) {
    const unsigned char* Ab = &Als[kt & 1][0];
    const unsigned char* Bb = &Bls[kt & 1][0];
    STAGE_A(kt + 1)                    // wraps on last iter (harmless, barrier-covered)
    i32x8 fb0, fb1, fb2, fb3;
    LDFRAG(Bb, boff[0], fb0) LDFRAG(Bb, boff[1], fb1)
    LDFRAG(Bb, boff[2], fb2) LDFRAG(Bb, boff[3], fb3)
#pragma unroll
    for (int mi = 0; mi < 4; ++mi) {
      i32x8 fa;
      LDFRAG(Ab, aoff[mi], fa)
      __builtin_amdgcn_s_setprio(1);
      MM(mi, 0, fa, fb0) MM(mi, 1, fa, fb1) MM(mi, 2, fa, fb2) MM(mi, 3, fa, fb3)
      __builtin_amdgcn_s_setprio(0);
    }
    STAGE_B(kt + 1)
#pragma unroll
    for (int mi = 4; mi < 8; ++mi) {
      i32x8 fa;
      LDFRAG(Ab, aoff[mi], fa)
      __builtin_amdgcn_s_setprio(1);
      MM(mi, 0, fa, fb0) MM(mi, 1, fa, fb1) MM(mi, 2, fa, fb2) MM(mi, 3, fa, fb3)
      __builtin_amdgcn_s_setprio(0);
    }
    asm volatile("s_waitcnt vmcnt(0)" ::: "memory");   // next tile's 8 stages done
    __builtin_amdgcn_s_barrier();
    __builtin_amdgcn_sched_barrier(0);
  }

  // Epilogue: per token row, sum exp(logit+bias) over tile's 256 vocab cols.
  // C/D layout: vocab col = lane&15 (+ni*16+wn*64), token row = (lane>>4)*4+reg (+mi*16+wm*128)
  __syncthreads();
  float bc[4];
#pragma unroll
  for (int ni = 0; ni < 4; ++ni) bc[ni] = bias[n0 + wn * 64 + ni * 16 + lr];
#pragma unroll
  for (int mi = 0; mi < 8; ++mi) {
    float s0 = 0.f, s1 = 0.f, s2 = 0.f, s3 = 0.f;
#pragma unroll
    for (int ni = 0; ni < 4; ++ni) {
      s0 += __expf(acc[mi][ni][0] + bc[ni]);
      s1 += __expf(acc[mi][ni][1] + bc[ni]);
      s2 += __expf(acc[mi][ni][2] + bc[ni]);
      s3 += __expf(acc[mi][ni][3] + bc[ni]);
    }
#pragma unroll
    for (int off = 1; off < 16; off <<= 1) {
      s0 += __shfl_xor(s0, off);
      s1 += __shfl_xor(s1, off);
      s2 += __shfl_xor(s2, off);
      s3 += __shfl_xor(s3, off);
    }
    if (lr == 0) {
      int rbase = wm * 128 + mi * 16 + lq * 4;
      red[rbase + 0][wn] = s0;
      red[rbase + 1][wn] = s1;
      red[rbase + 2][wn] = s2;
      red[rbase + 3][wn] = s3;
    }
  }
  __syncthreads();
  if (t < BM) {
    partial[(size_t)vt * T_TOK + m0 + t] = red[t][0] + red[t][1] + red[t][2] + red[t][3];
  }
}

// tgt[t] = dot(H[t], W[labels[t]]) + bias[labels[t]] in exact fp32 (one wave per token)
__global__ void tgt_kernel(const float* __restrict__ H, const float* __restrict__ W,
                           const float* __restrict__ bias, const int* __restrict__ labels,
                           float* __restrict__ tgt) {
  int tok = blockIdx.x * 4 + (threadIdx.x >> 6);
  int lane = threadIdx.x & 63;
  int lab = labels[tok];
  const float4* h = (const float4*)(H + (size_t)tok * DIM);
  const float4* w = (const float4*)(W + (size_t)lab * DIM);
  float s = 0.f;
#pragma unroll
  for (int j = 0; j < 4; ++j) {
    float4 a = h[lane + 64 * j];
    float4 bb = w[lane + 64 * j];
    s += a.x * bb.x + a.y * bb.y + a.z * bb.z + a.w * bb.w;
  }
#pragma unroll
  for (int off = 32; off > 0; off >>= 1) s += __shfl_xor(s, off);
  if (lane == 0) tgt[tok] = s + bias[lab];
}

// per-token: logz - tgt, weighted; wave-reduce -> per-block partials (deterministic)
__global__ void loss_a_kernel(const float* __restrict__ partial, const float* __restrict__ tgt,
                              const float* __restrict__ lw, float* __restrict__ npart,
                              float* __restrict__ dpart) {
  int tok = blockIdx.x * 64 + threadIdx.x;
  float s = 0.f;
  for (int v = 0; v < NVT; ++v) s += partial[(size_t)v * T_TOK + tok];
  float w = lw[tok];
  float num = w * (logf(s) - tgt[tok]);
#pragma unroll
  for (int off = 32; off > 0; off >>= 1) {
    num += __shfl_xor(num, off);
    w += __shfl_xor(w, off);
  }
  if (threadIdx.x == 0) {
    npart[blockIdx.x] = num;
    dpart[blockIdx.x] = w;
  }
}

__global__ void loss_b_kernel(const float* __restrict__ npart, const float* __restrict__ dpart,
                              float* __restrict__ out) {
  float num = npart[threadIdx.x];
  float den = dpart[threadIdx.x];
#pragma unroll
  for (int off = 32; off > 0; off >>= 1) {
    num += __shfl_xor(num, off);
    den += __shfl_xor(den, off);
  }
  if (threadIdx.x == 0) out[0] = num / den;
}

extern "C" void kernel_launch(void* const* d_in, const int* in_sizes, int n_in,
                              void* d_out, int out_size, void* d_ws, size_t ws_size,
                              hipStream_t stream) {
  const float* H = (const float*)d_in[0];
  const float* Wt = (const float*)d_in[1];
  const float* bias = (const float*)d_in[2];
  const int* labels = (const int*)d_in[3];
  const float* lw = (const float*)d_in[4];
  float* out = (float*)d_out;

  // ws layout (bytes):
  //   Wq  u8 [VOCAB][DIM]      = 32,768,000
  //   Hq  u8 [T_TOK][DIM]      =  4,194,304
  //   partial f32 [NVT][T_TOK] =  2,048,000
  //   tgt f32 [T_TOK]; npart/dpart f32 [64]x2
  char* ws = (char*)d_ws;
  unsigned char* Wq = (unsigned char*)ws;
  unsigned char* Hq = (unsigned char*)(ws + 32768000);
  float* partial = (float*)(ws + 32768000 + 4194304);
  float* tgt = (float*)(ws + 32768000 + 4194304 + 2048000);
  float* npart = tgt + T_TOK;
  float* dpart = npart + 64;

  hipLaunchKernelGGL(quant_kernel, dim3(((long long)VOCAB * DIM) / 4096), dim3(256), 0, stream,
                     Wt, Wq, (long long)VOCAB * DIM, 64.0f);   // W x 2^6
  hipLaunchKernelGGL(quant_kernel, dim3(((long long)T_TOK * DIM) / 4096), dim3(256), 0, stream,
                     H, Hq, (long long)T_TOK * DIM, 16.0f);    // H x 2^4
  hipLaunchKernelGGL(gemm_ce_kernel, dim3(NVT * NMT), dim3(512), 0, stream,
                     Hq, Wq, bias, partial);
  hipLaunchKernelGGL(tgt_kernel, dim3(T_TOK / 4), dim3(256), 0, stream,
                     H, Wt, bias, labels, tgt);
  hipLaunchKernelGGL(loss_a_kernel, dim3(T_TOK / 64), dim3(64), 0, stream,
                     partial, tgt, lw, npart, dpart);
  hipLaunchKernelGGL(loss_b_kernel, dim3(1), dim3(64), 0, stream,
                     npart, dpart, out);
}